// Round 1
// baseline (454.496 us; speedup 1.0000x reference)
//
#include <hip/hip_runtime.h>
#include <math.h>

#define NTGT 40000
#define NSRC 40000
#define NEDGE 640000

// ---------------- tiled row-chunk GEMM helper ----------------
// acc[i][j] += sum_k Xs[tr*4+i][k] * W[k][c0 + tc*4 + j]
__device__ __forceinline__ void gemm_chunk(const float (*Xs)[132], const float* __restrict__ W,
                                           int ldW, int c0, int tr, int tc, float acc[4][4]) {
  const float* wp = W + c0 + tc * 4;
#pragma unroll 4
  for (int k = 0; k < 128; ++k) {
    float4 b = *reinterpret_cast<const float4*>(wp + (size_t)k * ldW);
    float a[4];
#pragma unroll
    for (int i = 0; i < 4; ++i) a[i] = Xs[tr * 4 + i][k];
#pragma unroll
    for (int i = 0; i < 4; ++i) {
      acc[i][0] = fmaf(a[i], b.x, acc[i][0]);
      acc[i][1] = fmaf(a[i], b.y, acc[i][1]);
      acc[i][2] = fmaf(a[i], b.z, acc[i][2]);
      acc[i][3] = fmaf(a[i], b.w, acc[i][3]);
    }
  }
}

__device__ __forceinline__ float sigmoidf_fast(float x) {
  return 1.0f / (1.0f + __expf(-x));
}

// ---------------- target projections: Q, bt, g_tgt ----------------
__global__ __launch_bounds__(256) void k_tgt(const float* __restrict__ X,
                                             const float* __restrict__ Wq,
                                             const float* __restrict__ Wbt,
                                             const float* __restrict__ Wgt_w,
                                             const float* __restrict__ Wgt_b,
                                             float* __restrict__ Q,
                                             float* __restrict__ bt,
                                             float* __restrict__ gt) {
  __shared__ float Xs[64][132];
  const int tid = threadIdx.x;
  const int row0 = blockIdx.x * 64;
  for (int i = tid; i < 64 * 128; i += 256) {
    int r = i >> 7, c = i & 127;
    Xs[r][c] = X[(size_t)(row0 + r) * 128 + c];
  }
  __syncthreads();
  const int tr = tid >> 4, tc = tid & 15;

  // Q: 2 chunks of 64 cols
  for (int cc = 0; cc < 2; ++cc) {
    float acc[4][4] = {};
    gemm_chunk(Xs, Wq, 128, cc * 64, tr, tc, acc);
#pragma unroll
    for (int i = 0; i < 4; ++i)
#pragma unroll
      for (int j = 0; j < 4; ++j)
        Q[(size_t)(row0 + tr * 4 + i) * 128 + cc * 64 + tc * 4 + j] = acc[i][j];
  }
  // g_tgt: sigmoid(X @ Wgt_w + b)
  for (int cc = 0; cc < 2; ++cc) {
    float acc[4][4] = {};
    gemm_chunk(Xs, Wgt_w, 128, cc * 64, tr, tc, acc);
#pragma unroll
    for (int i = 0; i < 4; ++i)
#pragma unroll
      for (int j = 0; j < 4; ++j) {
        int col = cc * 64 + tc * 4 + j;
        gt[(size_t)(row0 + tr * 4 + i) * 128 + col] = sigmoidf_fast(acc[i][j] + Wgt_b[col]);
      }
  }
  // bt: 64 rows x 8 cols
  for (int o = tid; o < 64 * 8; o += 256) {
    int r = o >> 3, c = o & 7;
    float s = 0.f;
#pragma unroll 4
    for (int k = 0; k < 128; ++k) s = fmaf(Xs[r][k], Wbt[k * 8 + c], s);
    bt[(size_t)(row0 + r) * 8 + c] = s;
  }
}

// ---------------- source projections: K, bs, GV = sigmoid(gate) * V ----------------
__global__ __launch_bounds__(256) void k_src(const float* __restrict__ X,
                                             const float* __restrict__ Wkv,
                                             const float* __restrict__ Wbs,
                                             const float* __restrict__ Wgs_w,
                                             const float* __restrict__ Wgs_b,
                                             float* __restrict__ K,
                                             float* __restrict__ GV,
                                             float* __restrict__ bs) {
  __shared__ float Xs[64][132];
  const int tid = threadIdx.x;
  const int row0 = blockIdx.x * 64;
  for (int i = tid; i < 64 * 128; i += 256) {
    int r = i >> 7, c = i & 127;
    Xs[r][c] = X[(size_t)(row0 + r) * 128 + c];
  }
  __syncthreads();
  const int tr = tid >> 4, tc = tid & 15;

  // K: Wkv cols [0,128)
  for (int cc = 0; cc < 2; ++cc) {
    float acc[4][4] = {};
    gemm_chunk(Xs, Wkv, 256, cc * 64, tr, tc, acc);
#pragma unroll
    for (int i = 0; i < 4; ++i)
#pragma unroll
      for (int j = 0; j < 4; ++j)
        K[(size_t)(row0 + tr * 4 + i) * 128 + cc * 64 + tc * 4 + j] = acc[i][j];
  }
  // GV: sigmoid(X@Wgs + b) * V, V = Wkv cols [128,256)
  for (int cc = 0; cc < 2; ++cc) {
    float accV[4][4] = {};
    float accG[4][4] = {};
    gemm_chunk(Xs, Wkv, 256, 128 + cc * 64, tr, tc, accV);
    gemm_chunk(Xs, Wgs_w, 128, cc * 64, tr, tc, accG);
#pragma unroll
    for (int i = 0; i < 4; ++i)
#pragma unroll
      for (int j = 0; j < 4; ++j) {
        int col = cc * 64 + tc * 4 + j;
        float g = sigmoidf_fast(accG[i][j] + Wgs_b[col]);
        GV[(size_t)(row0 + tr * 4 + i) * 128 + col] = g * accV[i][j];
      }
  }
  // bs
  for (int o = tid; o < 64 * 8; o += 256) {
    int r = o >> 3, c = o & 7;
    float s = 0.f;
#pragma unroll 4
    for (int k = 0; k < 128; ++k) s = fmaf(Xs[r][k], Wbs[k * 8 + c], s);
    bs[(size_t)(row0 + r) * 8 + c] = s;
  }
}

// ---------------- CSR build ----------------
__global__ void k_hist(const int* __restrict__ inc_tgt, int* __restrict__ cnt) {
  int e = blockIdx.x * 256 + threadIdx.x;
  if (e < NEDGE) atomicAdd(&cnt[inc_tgt[e]], 1);
}

__global__ __launch_bounds__(1024) void k_scan(const int* __restrict__ cnt,
                                               int* __restrict__ rowstart, int n) {
  __shared__ int sd[1024];
  __shared__ int soff_s;
  const int tid = threadIdx.x;
  if (tid == 0) soff_s = 0;
  __syncthreads();
  for (int base = 0; base < n; base += 1024) {
    int i = base + tid;
    int v = (i < n) ? cnt[i] : 0;
    sd[tid] = v;
    __syncthreads();
    for (int d = 1; d < 1024; d <<= 1) {
      int t = (tid >= d) ? sd[tid - d] : 0;
      __syncthreads();
      sd[tid] += t;
      __syncthreads();
    }
    int incl = sd[tid];
    int total = sd[1023];
    int soff = soff_s;
    if (i < n) rowstart[i] = soff + incl - v;
    __syncthreads();
    if (tid == 0) soff_s = soff + total;
    __syncthreads();
  }
  if (tid == 0) rowstart[n] = soff_s;
}

__global__ void k_scatter(const int* __restrict__ inc_tgt, const int* __restrict__ rowstart,
                          int* __restrict__ cur, int* __restrict__ elist) {
  int e = blockIdx.x * 256 + threadIdx.x;
  if (e < NEDGE) {
    int t = inc_tgt[e];
    int pos = atomicAdd(&cur[t], 1);
    elist[rowstart[t] + pos] = e;
  }
}

// ---------------- per-target online-softmax attention ----------------
// one wave per target; lane l owns dims (2l, 2l+1); head h = l>>3
__global__ __launch_bounds__(256) void k_attn(const float* __restrict__ Q,
                                              const float* __restrict__ K,
                                              const float* __restrict__ GV,
                                              const float* __restrict__ bt,
                                              const float* __restrict__ bs,
                                              const float* __restrict__ gt,
                                              const int* __restrict__ rowstart,
                                              const int* __restrict__ elist,
                                              const int* __restrict__ inc_src,
                                              float* __restrict__ tmp) {
  const int wave = threadIdx.x >> 6;
  const int lane = threadIdx.x & 63;
  const int t = blockIdx.x * 4 + wave;  // 10000*4 == 40000 exact
  const int h = lane >> 3;

  float2 qv = reinterpret_cast<const float2*>(Q + (size_t)t * 128)[lane];
  const float bth = bt[(size_t)t * 8 + h];
  const int rs = rowstart[t], re = rowstart[t + 1];

  float m = -INFINITY, ssum = 0.f, a0 = 0.f, a1 = 0.f;
  for (int i = rs; i < re; ++i) {
    int e = elist[i];
    int s = inc_src[e];
    float2 kv = reinterpret_cast<const float2*>(K + (size_t)s * 128)[lane];
    float2 gv = reinterpret_cast<const float2*>(GV + (size_t)s * 128)[lane];
    float part = qv.x * kv.x + qv.y * kv.y;
    part += __shfl_xor(part, 1);
    part += __shfl_xor(part, 2);
    part += __shfl_xor(part, 4);
    float sc = part * 0.25f + bth + bs[(size_t)s * 8 + h];
    float mn = fmaxf(m, sc);
    float corr = __expf(m - mn);  // first iter: exp(-inf) = 0
    float p = __expf(sc - mn);
    ssum = ssum * corr + p;
    a0 = a0 * corr + p * gv.x;
    a1 = a1 * corr + p * gv.y;
    m = mn;
  }
  float inv = 1.f / (ssum + 1e-12f);
  float2 g = reinterpret_cast<const float2*>(gt + (size_t)t * 128)[lane];
  float2 o;
  o.x = g.x * a0 * inv;
  o.y = g.y * a1 * inv;
  reinterpret_cast<float2*>(tmp + (size_t)t * 128)[lane] = o;
}

// ---------------- final GEMM: out = tmp @ Wo ----------------
__global__ __launch_bounds__(256) void k_out(const float* __restrict__ tmp,
                                             const float* __restrict__ Wo,
                                             float* __restrict__ out) {
  __shared__ float Xs[64][132];
  const int tid = threadIdx.x;
  const int row0 = blockIdx.x * 64;
  for (int i = tid; i < 64 * 128; i += 256) {
    int r = i >> 7, c = i & 127;
    Xs[r][c] = tmp[(size_t)(row0 + r) * 128 + c];
  }
  __syncthreads();
  const int tr = tid >> 4, tc = tid & 15;
  for (int cc = 0; cc < 2; ++cc) {
    float acc[4][4] = {};
    gemm_chunk(Xs, Wo, 128, cc * 64, tr, tc, acc);
#pragma unroll
    for (int i = 0; i < 4; ++i)
#pragma unroll
      for (int j = 0; j < 4; ++j)
        out[(size_t)(row0 + tr * 4 + i) * 128 + cc * 64 + tc * 4 + j] = acc[i][j];
  }
}

extern "C" void kernel_launch(void* const* d_in, const int* in_sizes, int n_in,
                              void* d_out, int out_size, void* d_ws, size_t ws_size,
                              hipStream_t stream) {
  const float* X_tgt = (const float*)d_in[0];
  const float* X_src = (const float*)d_in[1];
  const int* inc_tgt = (const int*)d_in[2];
  const int* inc_src = (const int*)d_in[3];
  // d_in[4] = num_tgt (scalar, known = 40000)
  const float* Wq    = (const float*)d_in[5];
  const float* Wkv   = (const float*)d_in[6];
  const float* Wbt   = (const float*)d_in[7];
  const float* Wbs   = (const float*)d_in[8];
  const float* Wgt_w = (const float*)d_in[9];
  const float* Wgt_b = (const float*)d_in[10];
  const float* Wgs_w = (const float*)d_in[11];
  const float* Wgs_b = (const float*)d_in[12];
  const float* Wo    = (const float*)d_in[13];
  float* out = (float*)d_out;

  char* ws = (char*)d_ws;
  float* Q  = (float*)ws; ws += (size_t)NTGT * 128 * 4;
  float* K  = (float*)ws; ws += (size_t)NSRC * 128 * 4;
  float* GV = (float*)ws; ws += (size_t)NSRC * 128 * 4;
  float* gt = (float*)ws; ws += (size_t)NTGT * 128 * 4;
  float* bt = (float*)ws; ws += (size_t)NTGT * 8 * 4;
  float* bs = (float*)ws; ws += (size_t)NSRC * 8 * 4;
  int* rowstart = (int*)ws; ws += (size_t)(NTGT + 1) * 4;
  int* cnt = (int*)ws; ws += (size_t)NTGT * 4;
  int* cur = (int*)ws; ws += (size_t)NTGT * 4;
  int* elist = (int*)ws; ws += (size_t)NEDGE * 4;
  float* tmp = Q;  // safe alias: each wave reads its Q row before writing its tmp row

  hipMemsetAsync(cnt, 0, (size_t)NTGT * 4, stream);
  hipMemsetAsync(cur, 0, (size_t)NTGT * 4, stream);

  k_tgt<<<NTGT / 64, 256, 0, stream>>>(X_tgt, Wq, Wbt, Wgt_w, Wgt_b, Q, bt, gt);
  k_src<<<NSRC / 64, 256, 0, stream>>>(X_src, Wkv, Wbs, Wgs_w, Wgs_b, K, GV, bs);
  k_hist<<<NEDGE / 256, 256, 0, stream>>>(inc_tgt, cnt);
  k_scan<<<1, 1024, 0, stream>>>(cnt, rowstart, NTGT);
  k_scatter<<<NEDGE / 256, 256, 0, stream>>>(inc_tgt, rowstart, cnt /*unused*/ == nullptr ? cnt : cur, elist);
  k_attn<<<NTGT / 4, 256, 0, stream>>>(Q, K, GV, bt, bs, gt, rowstart, elist, inc_src, tmp);
  k_out<<<NTGT / 64, 256, 0, stream>>>(tmp, Wo, out);
}

// Round 2
// 259.845 us; speedup vs baseline: 1.7491x; 1.7491x over previous
//
#include <hip/hip_runtime.h>
#include <math.h>

#define NTGT 40000
#define NSRC 40000
#define NEDGE 640000

typedef __attribute__((ext_vector_type(8))) short bfrag;   // 8 bf16 in 4 VGPRs
typedef __attribute__((ext_vector_type(4))) short bhalf4;  // 4 bf16 (8B)
typedef __attribute__((ext_vector_type(4))) float f4acc;   // MFMA accumulator

__device__ __forceinline__ ushort f2bf(float f) {
  uint u = __float_as_uint(f);
  u += 0x7fffu + ((u >> 16) & 1u);  // round-to-nearest-even
  return (ushort)(u >> 16);
}
__device__ __forceinline__ float bflo(uint u) { return __uint_as_float(u << 16); }
__device__ __forceinline__ float bfhi(uint u) { return __uint_as_float(u & 0xffff0000u); }
__device__ __forceinline__ float bf2f(short s) { return __uint_as_float(((uint)(ushort)s) << 16); }
__device__ __forceinline__ float sigmoidf_fast(float x) { return 1.0f / (1.0f + __expf(-x)); }

// ---------------- weight prep: transpose + bf16 convert ----------------
// WT[n][k] = bf16(W[k][off+n]); all matrices 128(K) x 128(N) views
__global__ __launch_bounds__(256) void k_wprep(const float* __restrict__ Wq,
                                               const float* __restrict__ Wkv,
                                               const float* __restrict__ Wgt_w,
                                               const float* __restrict__ Wgs_w,
                                               const float* __restrict__ Wo,
                                               short* __restrict__ WqT, short* __restrict__ WkT,
                                               short* __restrict__ WvT, short* __restrict__ WgtT,
                                               short* __restrict__ WgsT, short* __restrict__ WoT) {
  int m = blockIdx.x >> 6;
  int idx = (blockIdx.x & 63) * 256 + threadIdx.x;  // 0..16383
  int n = idx >> 7, k = idx & 127;
  const float* src;
  int ld, off;
  short* dst;
  switch (m) {
    case 0: src = Wq;    ld = 128; off = 0;   dst = WqT;  break;
    case 1: src = Wkv;   ld = 256; off = 0;   dst = WkT;  break;
    case 2: src = Wkv;   ld = 256; off = 128; dst = WvT;  break;
    case 3: src = Wgt_w; ld = 128; off = 0;   dst = WgtT; break;
    case 4: src = Wgs_w; ld = 128; off = 0;   dst = WgsT; break;
    default:src = Wo;    ld = 128; off = 0;   dst = WoT;  break;
  }
  dst[n * 128 + k] = (short)f2bf(src[(size_t)k * ld + off + n]);
}

// ---------------- MFMA GEMM building blocks ----------------
// stage 64 fp32 rows -> LDS bf16, row stride 136 shorts (16B-aligned)
__device__ __forceinline__ void stage_rows_f32(const float* __restrict__ X, size_t row0,
                                               short (*Xs)[136], int tid) {
  for (int i = tid; i < 64 * 32; i += 256) {
    int r = i >> 5, c4 = (i & 31) * 4;
    float4 v = *reinterpret_cast<const float4*>(X + (row0 + r) * 128 + c4);
    bhalf4 o;
    o[0] = (short)f2bf(v.x); o[1] = (short)f2bf(v.y);
    o[2] = (short)f2bf(v.z); o[3] = (short)f2bf(v.w);
    *reinterpret_cast<bhalf4*>(&Xs[r][c4]) = o;
  }
}
__device__ __forceinline__ void stage_rows_bf16(const short* __restrict__ X, size_t row0,
                                                short (*Xs)[136], int tid) {
  for (int i = tid; i < 64 * 32; i += 256) {
    int r = i >> 5, c4 = (i & 31) * 4;
    *reinterpret_cast<bhalf4*>(&Xs[r][c4]) =
        *reinterpret_cast<const bhalf4*>(X + (row0 + r) * 128 + c4);
  }
}

// one wave: 16 rows x 128 cols += Xs(16x128) @ W(128x128), W given transposed (N x K)
__device__ __forceinline__ void mfma_pass(const short (*Xs)[136], int wave, int lane,
                                          const short* __restrict__ WT, f4acc acc[8]) {
  const int rl = wave * 16 + (lane & 15);
  const int kg = (lane >> 4) * 8;
  const int nl = lane & 15;
#pragma unroll
  for (int ks = 0; ks < 4; ++ks) {
    bfrag a = *reinterpret_cast<const bfrag*>(&Xs[rl][ks * 32 + kg]);
#pragma unroll
    for (int nf = 0; nf < 8; ++nf) {
      bfrag b = *reinterpret_cast<const bfrag*>(WT + (size_t)(nf * 16 + nl) * 128 + ks * 32 + kg);
      acc[nf] = __builtin_amdgcn_mfma_f32_16x16x32_bf16(a, b, acc[nf], 0, 0, 0);
    }
  }
}

// ---------------- target projections: Q(bf16), g_tgt(bf16), bt(f32) ----------------
__global__ __launch_bounds__(256) void k_tgt(const float* __restrict__ X,
                                             const short* __restrict__ WqT,
                                             const short* __restrict__ WgtT,
                                             const float* __restrict__ Wbt,
                                             const float* __restrict__ Wgt_b,
                                             short* __restrict__ Qb, short* __restrict__ gtb,
                                             float* __restrict__ bt) {
  __shared__ short Xs[64][136];
  const int tid = threadIdx.x;
  const size_t row0 = (size_t)blockIdx.x * 64;
  stage_rows_f32(X, row0, Xs, tid);
  __syncthreads();
  const int wave = tid >> 6, lane = tid & 63;
  const int rbase = (int)row0 + wave * 16 + ((lane >> 4) << 2);
  const int cl = lane & 15;
  {
    f4acc acc[8] = {};
    mfma_pass(Xs, wave, lane, WqT, acc);
#pragma unroll
    for (int nf = 0; nf < 8; ++nf)
#pragma unroll
      for (int j = 0; j < 4; ++j)
        Qb[(size_t)(rbase + j) * 128 + nf * 16 + cl] = (short)f2bf(acc[nf][j]);
  }
  {
    f4acc acc[8] = {};
    mfma_pass(Xs, wave, lane, WgtT, acc);
#pragma unroll
    for (int nf = 0; nf < 8; ++nf)
#pragma unroll
      for (int j = 0; j < 4; ++j) {
        int col = nf * 16 + cl;
        gtb[(size_t)(rbase + j) * 128 + col] =
            (short)f2bf(sigmoidf_fast(acc[nf][j] + Wgt_b[col]));
      }
  }
  for (int o = tid; o < 64 * 8; o += 256) {
    int r = o >> 3, c = o & 7;
    float s = 0.f;
#pragma unroll 4
    for (int k = 0; k < 128; ++k) s = fmaf(bf2f(Xs[r][k]), Wbt[k * 8 + c], s);
    bt[(row0 + r) * 8 + c] = s;
  }
}

// ---------------- source projections: K(bf16), GV(bf16), bs(f32) ----------------
__global__ __launch_bounds__(256) void k_src(const float* __restrict__ X,
                                             const short* __restrict__ WkT,
                                             const short* __restrict__ WvT,
                                             const short* __restrict__ WgsT,
                                             const float* __restrict__ Wbs,
                                             const float* __restrict__ Wgs_b,
                                             short* __restrict__ Kb, short* __restrict__ GVb,
                                             float* __restrict__ bs) {
  __shared__ short Xs[64][136];
  const int tid = threadIdx.x;
  const size_t row0 = (size_t)blockIdx.x * 64;
  stage_rows_f32(X, row0, Xs, tid);
  __syncthreads();
  const int wave = tid >> 6, lane = tid & 63;
  const int rbase = (int)row0 + wave * 16 + ((lane >> 4) << 2);
  const int cl = lane & 15;
  {
    f4acc acc[8] = {};
    mfma_pass(Xs, wave, lane, WkT, acc);
#pragma unroll
    for (int nf = 0; nf < 8; ++nf)
#pragma unroll
      for (int j = 0; j < 4; ++j)
        Kb[(size_t)(rbase + j) * 128 + nf * 16 + cl] = (short)f2bf(acc[nf][j]);
  }
  {
    f4acc aV[8] = {};
    f4acc aG[8] = {};
    const int rl = wave * 16 + (lane & 15);
    const int kg = (lane >> 4) * 8;
    const int nl = lane & 15;
#pragma unroll
    for (int ks = 0; ks < 4; ++ks) {
      bfrag a = *reinterpret_cast<const bfrag*>(&Xs[rl][ks * 32 + kg]);
#pragma unroll
      for (int nf = 0; nf < 8; ++nf) {
        bfrag bv = *reinterpret_cast<const bfrag*>(WvT + (size_t)(nf * 16 + nl) * 128 + ks * 32 + kg);
        aV[nf] = __builtin_amdgcn_mfma_f32_16x16x32_bf16(a, bv, aV[nf], 0, 0, 0);
        bfrag bg = *reinterpret_cast<const bfrag*>(WgsT + (size_t)(nf * 16 + nl) * 128 + ks * 32 + kg);
        aG[nf] = __builtin_amdgcn_mfma_f32_16x16x32_bf16(a, bg, aG[nf], 0, 0, 0);
      }
    }
#pragma unroll
    for (int nf = 0; nf < 8; ++nf)
#pragma unroll
      for (int j = 0; j < 4; ++j) {
        int col = nf * 16 + cl;
        float g = sigmoidf_fast(aG[nf][j] + Wgs_b[col]);
        GVb[(size_t)(rbase + j) * 128 + col] = (short)f2bf(g * aV[nf][j]);
      }
  }
  for (int o = tid; o < 64 * 8; o += 256) {
    int r = o >> 3, c = o & 7;
    float s = 0.f;
#pragma unroll 4
    for (int k = 0; k < 128; ++k) s = fmaf(bf2f(Xs[r][k]), Wbs[k * 8 + c], s);
    bs[(row0 + r) * 8 + c] = s;
  }
}

// ---------------- CSR build ----------------
__global__ void k_hist(const int* __restrict__ inc_tgt, int* __restrict__ cnt) {
  int e = blockIdx.x * 256 + threadIdx.x;
  if (e < NEDGE) atomicAdd(&cnt[inc_tgt[e]], 1);
}

__global__ __launch_bounds__(1024) void k_scan1(const int* __restrict__ cnt,
                                                int* __restrict__ rowstart,
                                                int* __restrict__ bsum) {
  __shared__ int wsum[16];
  const int tid = threadIdx.x;
  int i = blockIdx.x * 1024 + tid;
  int v = (i < NTGT) ? cnt[i] : 0;
  int lane = tid & 63, w = tid >> 6;
  int incl = v;
#pragma unroll
  for (int d = 1; d < 64; d <<= 1) {
    int t = __shfl_up(incl, d);
    if (lane >= d) incl += t;
  }
  if (lane == 63) wsum[w] = incl;
  __syncthreads();
  if (tid < 16) {
    int s = wsum[tid];
#pragma unroll
    for (int d = 1; d < 16; d <<= 1) {
      int t = __shfl_up(s, d);
      if (tid >= d) s += t;
    }
    wsum[tid] = s;
  }
  __syncthreads();
  int excl = incl - v + (w ? wsum[w - 1] : 0);
  if (i < NTGT) rowstart[i] = excl;
  if (tid == 1023) bsum[blockIdx.x] = wsum[15];
}

__global__ void k_scan2(const int* __restrict__ bsum, int* __restrict__ boff,
                        int* __restrict__ rowstart) {
  int lane = threadIdx.x;  // 64 threads
  int v = (lane < 40) ? bsum[lane] : 0;
  int incl = v;
#pragma unroll
  for (int d = 1; d < 64; d <<= 1) {
    int t = __shfl_up(incl, d);
    if (lane >= d) incl += t;
  }
  if (lane < 40) boff[lane] = incl - v;
  if (lane == 39) rowstart[NTGT] = incl;
}

__global__ void k_scan3(int* __restrict__ rowstart, const int* __restrict__ boff) {
  int i = blockIdx.x * 1024 + threadIdx.x;
  if (i < NTGT) rowstart[i] += boff[i >> 10];
}

// scatter SOURCE index (not edge id) — removes one gather from the hot loop
__global__ void k_scatter(const int* __restrict__ inc_tgt, const int* __restrict__ inc_src,
                          const int* __restrict__ rowstart, int* __restrict__ cur,
                          int* __restrict__ elist) {
  int e = blockIdx.x * 256 + threadIdx.x;
  if (e < NEDGE) {
    int t = inc_tgt[e];
    int pos = atomicAdd(&cur[t], 1);
    elist[rowstart[t] + pos] = inc_src[e];
  }
}

// ---------------- per-target online-softmax attention (bf16 tables) ----------------
__global__ __launch_bounds__(256) void k_attn(const short* __restrict__ Qb,
                                              const short* __restrict__ Kb,
                                              const short* __restrict__ GVb,
                                              const float* __restrict__ bt,
                                              const float* __restrict__ bs,
                                              const short* __restrict__ gtb,
                                              const int* __restrict__ rowstart,
                                              const int* __restrict__ elist,
                                              short* __restrict__ tmpb) {
  const int wave = threadIdx.x >> 6;
  const int lane = threadIdx.x & 63;
  const int t = blockIdx.x * 4 + wave;  // 10000*4 == 40000
  const int h = lane >> 3;
  const uint* Qp = (const uint*)Qb;
  const uint* Kp = (const uint*)Kb;
  const uint* Gp = (const uint*)GVb;
  const uint* gtp = (const uint*)gtb;

  uint qu = Qp[(size_t)t * 64 + lane];
  float qx = bflo(qu), qy = bfhi(qu);
  const float bth = bt[(size_t)t * 8 + h];
  const int rs = rowstart[t], re = rowstart[t + 1];

  float m = -INFINITY, ssum = 0.f, a0 = 0.f, a1 = 0.f;
  int s = (rs < re) ? elist[rs] : 0;
  for (int i = rs; i < re; ++i) {
    int scur = s;
    if (i + 1 < re) s = elist[i + 1];
    uint uk = Kp[(size_t)scur * 64 + lane];
    uint ug = Gp[(size_t)scur * 64 + lane];
    float bsv = bs[(size_t)scur * 8 + h];
    float part = qx * bflo(uk) + qy * bfhi(uk);
    part += __shfl_xor(part, 1);
    part += __shfl_xor(part, 2);
    part += __shfl_xor(part, 4);
    float sc = part * 0.25f + bth + bsv;
    float mn = fmaxf(m, sc);
    float corr = __expf(m - mn);
    float p = __expf(sc - mn);
    ssum = ssum * corr + p;
    a0 = a0 * corr + p * bflo(ug);
    a1 = a1 * corr + p * bfhi(ug);
    m = mn;
  }
  float inv = 1.f / (ssum + 1e-12f);
  uint g2 = gtp[(size_t)t * 64 + lane];
  float ox = bflo(g2) * a0 * inv;
  float oy = bfhi(g2) * a1 * inv;
  uint packed = ((uint)f2bf(ox)) | (((uint)f2bf(oy)) << 16);
  ((uint*)tmpb)[(size_t)t * 64 + lane] = packed;
}

// ---------------- final GEMM: out = tmp @ Wo (fp32 out) ----------------
__global__ __launch_bounds__(256) void k_out(const short* __restrict__ tmpb,
                                             const short* __restrict__ WoT,
                                             float* __restrict__ out) {
  __shared__ short Xs[64][136];
  const int tid = threadIdx.x;
  const size_t row0 = (size_t)blockIdx.x * 64;
  stage_rows_bf16(tmpb, row0, Xs, tid);
  __syncthreads();
  const int wave = tid >> 6, lane = tid & 63;
  const int rbase = (int)row0 + wave * 16 + ((lane >> 4) << 2);
  const int cl = lane & 15;
  f4acc acc[8] = {};
  mfma_pass(Xs, wave, lane, WoT, acc);
#pragma unroll
  for (int nf = 0; nf < 8; ++nf)
#pragma unroll
    for (int j = 0; j < 4; ++j)
      out[(size_t)(rbase + j) * 128 + nf * 16 + cl] = acc[nf][j];
}

extern "C" void kernel_launch(void* const* d_in, const int* in_sizes, int n_in,
                              void* d_out, int out_size, void* d_ws, size_t ws_size,
                              hipStream_t stream) {
  const float* X_tgt = (const float*)d_in[0];
  const float* X_src = (const float*)d_in[1];
  const int* inc_tgt = (const int*)d_in[2];
  const int* inc_src = (const int*)d_in[3];
  const float* Wq    = (const float*)d_in[5];
  const float* Wkv   = (const float*)d_in[6];
  const float* Wbt   = (const float*)d_in[7];
  const float* Wbs   = (const float*)d_in[8];
  const float* Wgt_w = (const float*)d_in[9];
  const float* Wgt_b = (const float*)d_in[10];
  const float* Wgs_w = (const float*)d_in[11];
  const float* Wgs_b = (const float*)d_in[12];
  const float* Wo    = (const float*)d_in[13];
  float* out = (float*)d_out;

  char* ws = (char*)d_ws;
  short* Qb   = (short*)ws; ws += (size_t)NTGT * 128 * 2;
  short* Kb   = (short*)ws; ws += (size_t)NSRC * 128 * 2;
  short* GVb  = (short*)ws; ws += (size_t)NSRC * 128 * 2;
  short* gtb  = (short*)ws; ws += (size_t)NTGT * 128 * 2;
  short* tmpb = (short*)ws; ws += (size_t)NTGT * 128 * 2;
  float* bt   = (float*)ws; ws += (size_t)NTGT * 8 * 4;
  float* bs   = (float*)ws; ws += (size_t)NSRC * 8 * 4;
  int* rowstart = (int*)ws; ws += (size_t)(NTGT + 4) * 4;
  int* cnt  = (int*)ws; ws += (size_t)NTGT * 4;
  int* cur  = (int*)ws; ws += (size_t)NTGT * 4;
  int* elist = (int*)ws; ws += (size_t)NEDGE * 4;
  int* bsum = (int*)ws; ws += 64 * 4;
  int* boff = (int*)ws; ws += 64 * 4;
  short* WqT  = (short*)ws; ws += 128 * 128 * 2;
  short* WkT  = (short*)ws; ws += 128 * 128 * 2;
  short* WvT  = (short*)ws; ws += 128 * 128 * 2;
  short* WgtT = (short*)ws; ws += 128 * 128 * 2;
  short* WgsT = (short*)ws; ws += 128 * 128 * 2;
  short* WoT  = (short*)ws; ws += 128 * 128 * 2;

  hipMemsetAsync(cnt, 0, (size_t)NTGT * 4, stream);
  hipMemsetAsync(cur, 0, (size_t)NTGT * 4, stream);

  k_wprep<<<6 * 64, 256, 0, stream>>>(Wq, Wkv, Wgt_w, Wgs_w, Wo, WqT, WkT, WvT, WgtT, WgsT, WoT);
  k_tgt<<<NTGT / 64, 256, 0, stream>>>(X_tgt, WqT, WgtT, Wbt, Wgt_b, Qb, gtb, bt);
  k_src<<<NSRC / 64, 256, 0, stream>>>(X_src, WkT, WvT, WgsT, Wbs, Wgs_b, Kb, GVb, bs);
  k_hist<<<NEDGE / 256, 256, 0, stream>>>(inc_tgt, cnt);
  k_scan1<<<40, 1024, 0, stream>>>(cnt, rowstart, bsum);
  k_scan2<<<1, 64, 0, stream>>>(bsum, boff, rowstart);
  k_scan3<<<40, 1024, 0, stream>>>(rowstart, boff);
  k_scatter<<<NEDGE / 256, 256, 0, stream>>>(inc_tgt, inc_src, rowstart, cur, elist);
  k_attn<<<NTGT / 4, 256, 0, stream>>>(Qb, Kb, GVb, bt, bs, gtb, rowstart, elist, tmpb);
  k_out<<<NTGT / 64, 256, 0, stream>>>(tmpb, WoT, out);
}